// Round 6
// baseline (220.254 us; speedup 1.0000x reference)
//
#include <hip/hip_runtime.h>
#include <math.h>

#define B_ 8
#define C_ 256
#define N_ 4096          // H*W
#define NPOS 32768       // B*N
#define SCALE_ 0.1767766952966369f
#define EPS_ 1e-5f

typedef __attribute__((ext_vector_type(8))) short bf16x8;
typedef __attribute__((ext_vector_type(8))) unsigned short u16x8;
typedef __attribute__((ext_vector_type(4))) float f32x4;

__device__ __forceinline__ unsigned short f2bf(float f) {
  union { float f; unsigned u; } v; v.f = f;
  unsigned r = v.u + 0x7fff + ((v.u >> 16) & 1);   // RNE
  return (unsigned short)(r >> 16);
}
__device__ __forceinline__ float bf2f(unsigned short u) {
  union { unsigned u; float f; } v; v.u = ((unsigned)u) << 16; return v.f;
}
__device__ __forceinline__ float blo(unsigned u) {
  union { unsigned u; float f; } v; v.u = u << 16; return v.f;
}
__device__ __forceinline__ float bhi(unsigned u) {
  union { unsigned u; float f; } v; v.u = u & 0xffff0000u; return v.f;
}

#define GLD_LDS16(g, l) \
  __builtin_amdgcn_global_load_lds((const __attribute__((address_space(1))) unsigned int*)(g), \
                                   (__attribute__((address_space(3))) unsigned int*)(l), 16, 0, 0)

// ---- kernel 1: [blocks 0..2047] sub+LN (16 positions each), [2048..2303] cvt
// Per LN block: 16 x-positions x 256 channels. Stats via register partial
// sums + wave shfl reduction (no LDS round-trip). bf16 tile, ~9 KB LDS.
__global__ __launch_bounds__(256) void k_pre(
    const float* __restrict__ vi, const float* __restrict__ ir,
    const float* __restrict__ wq, const float* __restrict__ pw,
    const float* __restrict__ ln_g, const float* __restrict__ ln_b,
    unsigned short* __restrict__ wdst,
    unsigned short* __restrict__ subB, unsigned short* __restrict__ viB,
    unsigned short* __restrict__ xn)
{
  __shared__ unsigned short tile[16 * 264];     // [x][c], stride 264
  __shared__ float redS[4][16], redS2[4][16];   // [wave][x]
  __shared__ float meanS[16], rstdS[16];
  int t = threadIdx.x;
  if (blockIdx.x >= 2048) {
    int i4 = (blockIdx.x - 2048) * 256 + t;     // 65536 float4s
    float4 v = (i4 < 49152) ? ((const float4*)wq)[i4] : ((const float4*)pw)[i4 - 49152];
    ushort4 o;
    o.x = f2bf(v.x); o.y = f2bf(v.y); o.z = f2bf(v.z); o.w = f2bf(v.w);
    ((ushort4*)wdst)[i4] = o;
    return;
  }
  int blk = blockIdx.x;                 // b*256 + y*4 + qtr
  int b = blk >> 8;
  int y = (blk >> 2) & 63;
  int qtr = blk & 3;
  int x0 = qtr * 16;
  int k = t & 3;                        // x-group (4 consecutive x)
  int w = t >> 6;
  float ps[4] = {0.f, 0.f, 0.f, 0.f}, ps2[4] = {0.f, 0.f, 0.f, 0.f};
  #pragma unroll
  for (int it = 0; it < 4; ++it) {
    int c = it * 64 + (t >> 2);
    size_t g = (((size_t)(b * 256 + c)) << 12) + y * 64 + x0 + k * 4;
    float4 v4 = *(const float4*)&vi[g];
    float4 i4 = *(const float4*)&ir[g];
    float s0 = v4.x - i4.x, s1 = v4.y - i4.y, s2 = v4.z - i4.z, s3 = v4.w - i4.w;
    ushort4 sb, vb;
    sb.x = f2bf(s0); sb.y = f2bf(s1); sb.z = f2bf(s2); sb.w = f2bf(s3);
    vb.x = f2bf(v4.x); vb.y = f2bf(v4.y); vb.z = f2bf(v4.z); vb.w = f2bf(v4.w);
    *(ushort4*)&subB[g] = sb;
    *(ushort4*)&viB[g] = vb;
    int xl = k * 4;
    tile[(xl + 0) * 264 + c] = sb.x;
    tile[(xl + 1) * 264 + c] = sb.y;
    tile[(xl + 2) * 264 + c] = sb.z;
    tile[(xl + 3) * 264 + c] = sb.w;
    ps[0] += s0; ps2[0] += s0 * s0;
    ps[1] += s1; ps2[1] += s1 * s1;
    ps[2] += s2; ps2[2] += s2 * s2;
    ps[3] += s3; ps2[3] += s3 * s3;
  }
  // reduce across the 16 lanes per wave that share x-group k
  #pragma unroll
  for (int j = 0; j < 4; ++j) {
    #pragma unroll
    for (int m = 4; m < 64; m <<= 1) {
      ps[j]  += __shfl_xor(ps[j],  m);
      ps2[j] += __shfl_xor(ps2[j], m);
    }
  }
  if ((t & 63) < 4) {
    #pragma unroll
    for (int j = 0; j < 4; ++j) {
      redS[w][k * 4 + j]  = ps[j];
      redS2[w][k * 4 + j] = ps2[j];
    }
  }
  __syncthreads();
  if (t < 16) {
    float s = redS[0][t] + redS[1][t] + redS[2][t] + redS[3][t];
    float s2 = redS2[0][t] + redS2[1][t] + redS2[2][t] + redS2[3][t];
    float mu = s * (1.f / 256.f);
    float var = s2 * (1.f / 256.f) - mu * mu;
    meanS[t] = mu;
    rstdS[t] = rsqrtf(var + EPS_);
  }
  __syncthreads();
  #pragma unroll
  for (int it2 = 0; it2 < 2; ++it2) {
    int item = it2 * 256 + t;
    int p = item >> 5, cg = item & 31;
    int c0 = cg * 8;
    u16x8 tv = *(const u16x8*)&tile[p * 264 + c0];
    float4 gl = *(const float4*)&ln_g[c0];
    float4 gh = *(const float4*)&ln_g[c0 + 4];
    float4 bl = *(const float4*)&ln_b[c0];
    float4 bh = *(const float4*)&ln_b[c0 + 4];
    float mu = meanS[p], rs = rstdS[p];
    u16x8 ov;
    ov[0] = f2bf((bf2f((unsigned short)tv[0]) - mu) * rs * gl.x + bl.x);
    ov[1] = f2bf((bf2f((unsigned short)tv[1]) - mu) * rs * gl.y + bl.y);
    ov[2] = f2bf((bf2f((unsigned short)tv[2]) - mu) * rs * gl.z + bl.z);
    ov[3] = f2bf((bf2f((unsigned short)tv[3]) - mu) * rs * gl.w + bl.w);
    ov[4] = f2bf((bf2f((unsigned short)tv[4]) - mu) * rs * gh.x + bh.x);
    ov[5] = f2bf((bf2f((unsigned short)tv[5]) - mu) * rs * gh.y + bh.y);
    ov[6] = f2bf((bf2f((unsigned short)tv[6]) - mu) * rs * gh.z + bh.z);
    ov[7] = f2bf((bf2f((unsigned short)tv[7]) - mu) * rs * gh.w + bh.w);
    *(u16x8*)&xn[((size_t)(b * 4096 + y * 64 + x0 + p)) * 256 + c0] = ov;
  }
}

// ---------------- MFMA GEMM: C[M,N] = A[M,256] * B[N,256]^T ----------------
// Flat grid, XCD-aware swizzle: blocks sharing one A m-tile land on one XCD.
template<int EPI, int NT>
__global__ __launch_bounds__(256) void k_gemm_mfma(
    const unsigned short* __restrict__ A,
    const unsigned short* __restrict__ Bw,
    unsigned short* __restrict__ Cout,
    const float* __restrict__ bias,
    const unsigned short* __restrict__ subB,
    int ldc)
{
  __shared__ __align__(16) unsigned short As[128 * 32];
  __shared__ __align__(16) unsigned short Bs[128 * 32];
  __shared__ __align__(16) unsigned short Cs[64 * 136];
  int flat = blockIdx.x;
  int xcd = flat & 7;
  int l = flat >> 3;
  int ml = l / NT;
  int nn = l - ml * NT;
  int m0 = (xcd * 32 + ml) * 128;
  int n0 = nn * 128;
  int tid = threadIdx.x;
  int wv = tid >> 6;
  int lane = tid & 63;
  int mw = (wv >> 1) * 64, nw = (wv & 1) * 64;
  int r = lane & 15, q = lane >> 4;

  int seg0 = wv * 2;
  int srow0 = seg0 * 16 + (lane >> 2);
  int scol = (lane & 3) * 8;
  const unsigned short* ga0 = A  + (size_t)(m0 + srow0) * 256 + scol;
  const unsigned short* ga1 = ga0 + 16 * 256;
  const unsigned short* gb0 = Bw + (size_t)(n0 + srow0) * 256 + scol;
  const unsigned short* gb1 = gb0 + 16 * 256;
  unsigned short* la0 = &As[seg0 * 512];
  unsigned short* la1 = la0 + 512;
  unsigned short* lb0 = &Bs[seg0 * 512];
  unsigned short* lb1 = lb0 + 512;

  f32x4 acc[4][4];
  #pragma unroll
  for (int i = 0; i < 4; ++i)
    #pragma unroll
    for (int j = 0; j < 4; ++j)
      acc[i][j] = (f32x4){0.f, 0.f, 0.f, 0.f};

  for (int k0 = 0; k0 < 256; k0 += 32) {
    GLD_LDS16(ga0 + k0, la0);
    GLD_LDS16(ga1 + k0, la1);
    GLD_LDS16(gb0 + k0, lb0);
    GLD_LDS16(gb1 + k0, lb1);
    __syncthreads();
    bf16x8 af[4], bfr[4];
    #pragma unroll
    for (int mt = 0; mt < 4; ++mt)
      af[mt] = *(const bf16x8*)&As[(mw + mt * 16 + r) * 32 + q * 8];
    #pragma unroll
    for (int nt = 0; nt < 4; ++nt)
      bfr[nt] = *(const bf16x8*)&Bs[(nw + nt * 16 + r) * 32 + q * 8];
    #pragma unroll
    for (int mt = 0; mt < 4; ++mt)
      #pragma unroll
      for (int nt = 0; nt < 4; ++nt)
        acc[mt][nt] = __builtin_amdgcn_mfma_f32_16x16x32_bf16(af[mt], bfr[nt], acc[mt][nt], 0, 0, 0);
    __syncthreads();
  }

  int b = m0 >> 12;
  int nn0 = m0 & 4095;
  #pragma unroll
  for (int pass = 0; pass < 2; ++pass) {
    __syncthreads();
    if (EPI == 0) {
      if ((wv >> 1) == pass) {
        #pragma unroll
        for (int mt = 0; mt < 4; ++mt) {
          int lr = mt * 16 + q * 4;
          #pragma unroll
          for (int nt = 0; nt < 4; ++nt) {
            int col = nw + nt * 16 + r;
            #pragma unroll
            for (int rr = 0; rr < 4; ++rr)
              Cs[(lr + rr) * 136 + col] = f2bf(acc[mt][nt][rr]);
          }
        }
      }
    } else {
      if ((wv & 1) == pass) {
        #pragma unroll
        for (int nt = 0; nt < 4; ++nt) {
          int lr = nt * 16 + r;
          #pragma unroll
          for (int mt = 0; mt < 4; ++mt) {
            int pc = mw + mt * 16 + q * 4;
            #pragma unroll
            for (int rr = 0; rr < 4; ++rr)
              Cs[lr * 136 + pc + rr] = f2bf(acc[mt][nt][rr]);
          }
        }
      }
    }
    __syncthreads();
    if (EPI == 0) {
      #pragma unroll
      for (int cc = 0; cc < 4; ++cc) {
        int ch = cc * 256 + tid;
        int row = ch >> 4, cg = ch & 15;
        u16x8 cv = *(const u16x8*)&Cs[row * 136 + cg * 8];
        int m = m0 + pass * 64 + row;
        *(u16x8*)&Cout[(size_t)m * ldc + n0 + cg * 8] = cv;
      }
    } else {
      #pragma unroll
      for (int cc = 0; cc < 4; ++cc) {
        int ch = cc * 256 + tid;
        int row = ch >> 4, cg = ch & 15;
        u16x8 cv = *(const u16x8*)&Cs[row * 136 + cg * 8];
        int c = n0 + pass * 64 + row;
        size_t idx = ((size_t)(b * 256 + c)) * 4096 + nn0 + cg * 8;
        u16x8 sv = *(const u16x8*)&subB[idx];
        float bb = bias[c];
        u16x8 ov;
        #pragma unroll
        for (int e = 0; e < 8; ++e)
          ov[e] = f2bf(bf2f((unsigned short)cv[e]) + bb + bf2f((unsigned short)sv[e]));
        *(u16x8*)&Cout[idx] = ov;
      }
    }
  }
}

// ---------------- kernel 3: dilated local attention ----------------
__global__ __launch_bounds__(256) void k_attn(
    const unsigned short* __restrict__ qkv,   // [NPOS, 768] bf16
    unsigned short* __restrict__ y)           // [NPOS, 256] bf16
{
  int t = threadIdx.x;
  int sub = t >> 2;
  int lane4 = t & 3;
  int item = blockIdx.x * 64 + sub;
  int ih = item & 7;
  int p = item >> 3;
  int i = ih >> 1, h = ih & 1;
  int dil = i + 1;
  int b = p >> 12;
  int n = p & 4095;
  int py = n >> 6, px = n & 63;
  int off = i * 64 + h * 32 + lane4 * 8;
  const unsigned short* base = qkv + off;

  uint4 qw = *(const uint4*)(base + (size_t)p * 768);
  float q0 = blo(qw.x), q1 = bhi(qw.x), q2 = blo(qw.y), q3 = bhi(qw.y),
        q4 = blo(qw.z), q5 = bhi(qw.z), q6 = blo(qw.w), q7 = bhi(qw.w);

  int pj[9];
  #pragma unroll
  for (int j = 0; j < 9; ++j) {
    int ny = py + (j / 3 - 1) * dil;
    int nx = px + (j % 3 - 1) * dil;
    bool ok = ((unsigned)ny < 64u) && ((unsigned)nx < 64u);
    pj[j] = ok ? ((b << 12) + (ny << 6) + nx) : -1;
  }

  float sc[9];
  #pragma unroll
  for (int j = 0; j < 9; ++j) {
    float s = 0.f;
    if (pj[j] >= 0) {
      uint4 kw = *(const uint4*)(base + 256 + (size_t)pj[j] * 768);
      s  = q0 * blo(kw.x) + q1 * bhi(kw.x);
      s += q2 * blo(kw.y) + q3 * bhi(kw.y);
      s += q4 * blo(kw.z) + q5 * bhi(kw.z);
      s += q6 * blo(kw.w) + q7 * bhi(kw.w);
    }
    s += __shfl_xor(s, 1, 4);
    s += __shfl_xor(s, 2, 4);
    sc[j] = s * SCALE_;             // zero-pad taps -> score exactly 0
  }

  float mx = sc[0];
  #pragma unroll
  for (int j = 1; j < 9; ++j) mx = fmaxf(mx, sc[j]);
  float e[9], ssum = 0.f;
  #pragma unroll
  for (int j = 0; j < 9; ++j) { e[j] = __expf(sc[j] - mx); ssum += e[j]; }
  float inv = 1.f / ssum;

  float o0 = 0.f, o1 = 0.f, o2 = 0.f, o3 = 0.f, o4 = 0.f, o5 = 0.f, o6 = 0.f, o7 = 0.f;
  #pragma unroll
  for (int j = 0; j < 9; ++j) {
    if (pj[j] >= 0) {
      float w = e[j] * inv;
      uint4 vw = *(const uint4*)(base + 512 + (size_t)pj[j] * 768);
      o0 += w * blo(vw.x); o1 += w * bhi(vw.x);
      o2 += w * blo(vw.y); o3 += w * bhi(vw.y);
      o4 += w * blo(vw.z); o5 += w * bhi(vw.z);
      o6 += w * blo(vw.w); o7 += w * bhi(vw.w);
    }
  }

  u16x8 ov;
  ov[0] = f2bf(o0); ov[1] = f2bf(o1); ov[2] = f2bf(o2); ov[3] = f2bf(o3);
  ov[4] = f2bf(o4); ov[5] = f2bf(o5); ov[6] = f2bf(o6); ov[7] = f2bf(o7);
  *(u16x8*)(y + (size_t)p * 256 + off) = ov;
}

// ---------------- kernel 5: per-(b,c) 64x64x64 MFMA matmul, dup output ----
__global__ __launch_bounds__(256) void k_bmm(
    const unsigned short* __restrict__ viB,
    const unsigned short* __restrict__ divmB,
    float* __restrict__ out)
{
  __shared__ __align__(16) unsigned short Vs[64 * 72];
  __shared__ __align__(16) unsigned short Ds[64 * 72];
  int bc = blockIdx.x;
  size_t base = (size_t)bc * 4096;
  int t = threadIdx.x;
  {
    int flat = t * 16;
    int row = flat >> 6, col = flat & 63;
    u16x8 v0 = *(const u16x8*)&viB[base + flat];
    u16x8 v1 = *(const u16x8*)&viB[base + flat + 8];
    *(u16x8*)&Vs[row * 72 + col] = v0;
    *(u16x8*)&Vs[row * 72 + col + 8] = v1;
    u16x8 d0 = *(const u16x8*)&divmB[base + flat];
    u16x8 d1 = *(const u16x8*)&divmB[base + flat + 8];
    #pragma unroll
    for (int e = 0; e < 8; ++e) {
      Ds[(col + e) * 72 + row] = (unsigned short)d0[e];
      Ds[(col + 8 + e) * 72 + row] = (unsigned short)d1[e];
    }
  }
  __syncthreads();
  int w = t >> 6, lane = t & 63;
  int r = lane & 15, q = lane >> 4;
  int wi = (w >> 1) * 32, wj = (w & 1) * 32;
  f32x4 acc[2][2];
  #pragma unroll
  for (int i = 0; i < 2; ++i)
    #pragma unroll
    for (int j = 0; j < 2; ++j)
      acc[i][j] = (f32x4){0.f, 0.f, 0.f, 0.f};
  #pragma unroll
  for (int ks = 0; ks < 2; ++ks) {
    bf16x8 a[2], bfr[2];
    #pragma unroll
    for (int ti = 0; ti < 2; ++ti)
      a[ti] = *(const bf16x8*)&Vs[(wi + ti * 16 + r) * 72 + ks * 32 + q * 8];
    #pragma unroll
    for (int tj = 0; tj < 2; ++tj)
      bfr[tj] = *(const bf16x8*)&Ds[(wj + tj * 16 + r) * 72 + ks * 32 + q * 8];
    #pragma unroll
    for (int ti = 0; ti < 2; ++ti)
      #pragma unroll
      for (int tj = 0; tj < 2; ++tj)
        acc[ti][tj] = __builtin_amdgcn_mfma_f32_16x16x32_bf16(a[ti], bfr[tj], acc[ti][tj], 0, 0, 0);
  }
  #pragma unroll
  for (int ti = 0; ti < 2; ++ti)
    #pragma unroll
    for (int tj = 0; tj < 2; ++tj)
      #pragma unroll
      for (int rr = 0; rr < 4; ++rr) {
        int row = wi + ti * 16 + q * 4 + rr;
        int col = wj + tj * 16 + r;
        float v = acc[ti][tj][rr];
        __builtin_nontemporal_store(v, &out[base + row * 64 + col]);
        __builtin_nontemporal_store(v, &out[8388608ull + base + row * 64 + col]);
      }
}

extern "C" void kernel_launch(void* const* d_in, const int* in_sizes, int n_in,
                              void* d_out, int out_size, void* d_ws, size_t ws_size,
                              hipStream_t stream) {
  const float* vi     = (const float*)d_in[0];
  const float* ir     = (const float*)d_in[1];
  const float* w_qkv  = (const float*)d_in[2];
  const float* proj_w = (const float*)d_in[3];
  const float* proj_b = (const float*)d_in[4];
  const float* ln_g   = (const float*)d_in[5];
  const float* ln_b   = (const float*)d_in[6];
  float* out = (float*)d_out;
  char* ws = (char*)d_ws;
  unsigned short* subB = (unsigned short*)(ws);                // 16.8 MB BCHW bf16
  unsigned short* qkvb = (unsigned short*)(ws + 16777216);     // 50.3 MB [NPOS,768]
  unsigned short* divmB= (unsigned short*)(ws + 16777216);     // reuse, 16.8 MB BCHW
  unsigned short* xnb  = (unsigned short*)(ws + 67108864);     // 16.8 MB [NPOS,256]
  unsigned short* yb   = (unsigned short*)(ws + 83886080);     // 16.8 MB [NPOS,256]
  unsigned short* viB  = (unsigned short*)(ws + 100663296);    // 16.8 MB BCHW bf16
  unsigned short* wqb  = (unsigned short*)(ws + 117440512);    // [768,256] bf16
  unsigned short* pwb  = wqb + 196608;                         // [256,256] bf16

  k_pre<<<2304, 256, 0, stream>>>(vi, ir, w_qkv, proj_w, ln_g, ln_b, wqb, subB, viB, xnb);
  k_gemm_mfma<0, 6><<<1536, 256, 0, stream>>>(xnb, wqb, qkvb, nullptr, nullptr, 768);
  k_attn<<<4096, 256, 0, stream>>>(qkvb, yb);
  k_gemm_mfma<1, 2><<<512, 256, 0, stream>>>(yb, pwb, divmB, proj_b, subB, 0);
  k_bmm<<<2048, 256, 0, stream>>>(viB, divmB, out);
}